// Round 10
// baseline (2611.877 us; speedup 1.0000x reference)
//
#include <hip/hip_runtime.h>
#include <stdint.h>

// Net_11587821765063: sequential SNN scan, T=1000 steps.
// Output = spike_out (T,1,COUT) float32 only; w / traces are not returned.
//
// Math reductions (absmax 0 in rounds 1-9):
//  - potentiation p[t][i] = 2 if x[t][i] else (1 if (t==0 or x[t-1][i]) else 0)
//  - depression for row o at t = -x[t][i] iff (!spike[t][o] && spike[t-1][o]),
//    spike[-1] := true (cout init quirk).
//  - prohibit P[t] = 1 iff any spike at t-1 (grid-wide 1-bit OR); P[0]=0.
//
// Round 10: decouple publish from resolve. r7/r9 lesson: publishing AFTER the
// barrier (which waits on P[u-1]) makes period = Δ/2 where Δ ≈ 7000 cyc is the
// full store->visible->detect chain; the barrier's vmcnt(0) drain also puts
// the publish-store ack inside every step. Fix:
//  - 128 single-wave blocks (64 thr), 4 rows/wave: NO __syncthreads, NO LDS,
//    no vmcnt drain. Math core = r8's validated 4-row branchy code.
//  - publish hb(u) BEFORE spinning on P[u-1]: t_pub(u)=t_P(u-2)+C, so
//    period = (C+Δ)/3 instead of Δ/2.
//  - direct gather (64 lanes x uint64 covers all 128 slot dwords), per-wave
//    P-recurrence (r7's p2/p3), no sleeps.
// 2-step speculation as r5-r9: block publishes 4 hypothesis bits at step u
// (any-own-row-spike under (P[u-1]=d, P[u]=c), bit k=(d<<1)|c); line(u)
// gathered at u+2; P[u-1]=A(u-2)[P[u-3]][P[u-2]]. Outputs lag one step.

#define T_STEPS 1000
#define CIN     784
#define COUT    512
#define CPL     13            // columns per lane (64*13 = 832 >= 784)
#define NBLK    128           // single-wave compute blocks
#define VTHR_F   12500.0f
#define PROHIB_F 11250.0f

#define SLOTS_WORDS (T_STEPS * NBLK)          // uint32 per (u, blk) = 128000
#define CODE_OFFSET 524288                    // 512 KiB >= 512000 B of slots

// ---- prep: zero slot words and pack per-(t,lane) 16-byte code slot:
// byte j (j<13) encodes col = lane*13+j: bit0 = x[t][col], bits[2:1] = p.
__global__ __launch_bounds__(256) void prep_kernel(const int* __restrict__ x,
                                                   uint8_t* __restrict__ code,
                                                   uint2* __restrict__ slots2) {
    int gid = blockIdx.x * blockDim.x + threadIdx.x;   // one per (t, lane)
    if (gid >= T_STEPS * 64) return;
    slots2[gid] = make_uint2(0u, 0u);                  // 64000 x 8B = 512000 B
    int t = gid >> 6;
    int lane = gid & 63;
    uint32_t wds[4] = {0u, 0u, 0u, 0u};
    #pragma unroll
    for (int j = 0; j < CPL; ++j) {
        int col = lane * CPL + j;
        uint32_t b = 0u;
        if (col < CIN) {
            int xc = x[t * CIN + col];
            int xp = (t > 0) ? x[(t - 1) * CIN + col] : 0;
            int p = xc ? 2 : ((t == 0) ? 1 : (xp ? 1 : 0));
            b = (uint32_t)((xc & 1) | (p << 1));
        }
        wds[j >> 2] |= b << ((j & 3) * 8);
    }
    ((uint4*)code)[gid] = make_uint4(wds[0], wds[1], wds[2], wds[3]);
}

__device__ __forceinline__ int rfl(bool b) {      // force SGPR / s_cbranch
    return __builtin_amdgcn_readfirstlane(b ? 1 : 0);
}

__global__ __launch_bounds__(64, 1) void snn_kernel(const float* __restrict__ weight,
                                                    const uint8_t* __restrict__ code,
                                                    uint32_t* __restrict__ slots,
                                                    float* __restrict__ out) {
    const int lane = threadIdx.x;          // one wave per block
    const int blk  = blockIdx.x;
    const int row0 = blk * 4;              // 4 consecutive rows

    float wA0[CPL], wA1[CPL], wA2[CPL], wA3[CPL];
    float wB0[CPL], wB1[CPL], wB2[CPL], wB3[CPL];
    #pragma unroll
    for (int j = 0; j < CPL; ++j) {
        int col = lane * CPL + j;
        bool in = (col < CIN);
        float v0 = in ? weight[(row0 + 0) * CIN + col] : 0.0f;
        float v1 = in ? weight[(row0 + 1) * CIN + col] : 0.0f;
        float v2 = in ? weight[(row0 + 2) * CIN + col] : 0.0f;
        float v3 = in ? weight[(row0 + 3) * CIN + col] : 0.0f;
        wA0[j] = v0; wB0[j] = v0;
        wA1[j] = v1; wB1[j] = v1;
        wA2[j] = v2; wB2[j] = v2;
        wA3[j] = v3; wB3[j] = v3;
    }

    const uint4* code4 = (const uint4*)code;
    uint4 cw  = code4[lane];               // codes for u=0
    uint4 cwn = code4[64 + lane];          // codes for u=1 (prefetch)

    float memA0 = 0, memA1 = 0, memA2 = 0, memA3 = 0;
    float memB0 = 0, memB1 = 0, memB2 = 0, memB3 = 0;
    bool psA0 = true, psA1 = true, psA2 = true, psA3 = true;  // spike(-1)=true
    bool psB0 = true, psB1 = true, psB2 = true, psB3 = true;
    bool eq0 = true, eq1 = true, eq2 = true, eq3 = true;      // wB==wA per row
    int p2 = 0, p3 = 0;                    // actual P[u-2], P[u-3]

    // r5/r8's validated 4-value folded butterfly (bit-identical per-sum tree)
    auto fold4 = [&](float d0, float d1, float d2, float d3,
                     float& S0, float& S1, float& S2, float& S3) {
        bool half = (lane & 32) != 0;
        float kx = half ? d2 : d0;
        float ky = half ? d3 : d1;
        float sx = half ? d0 : d2;
        float sy = half ? d1 : d3;
        kx += __shfl_xor(sx, 32, 64);
        ky += __shfl_xor(sy, 32, 64);
        bool subq = (lane & 16) != 0;
        float kk = subq ? ky : kx;
        float ss = subq ? kx : ky;
        kk += __shfl_xor(ss, 16, 64);
        kk += __shfl_xor(kk, 8, 64);
        kk += __shfl_xor(kk, 4, 64);
        kk += __shfl_xor(kk, 2, 64);
        kk += __shfl_xor(kk, 1, 64);
        float b1 = __shfl_xor(kk, 16, 64);
        float b2 = __shfl_xor(kk, 32, 64);
        float b3 = __shfl_xor(b1, 32, 64);
        int q = lane >> 4;
        S0 = (q == 0) ? kk : (q == 1) ? b1 : (q == 2) ? b2 : b3;
        S1 = (q == 0) ? b1 : (q == 1) ? kk : (q == 2) ? b3 : b2;
        S2 = (q == 0) ? b2 : (q == 1) ? b3 : (q == 2) ? kk : b1;
        S3 = (q == 0) ? b3 : (q == 1) ? b2 : (q == 2) ? b1 : kk;
    };

    for (int u = 0; u < T_STEPS; ++u) {
        // ---- early issue: gather line(u-2), 64 lanes x uint64 = 128 dwords
        const unsigned long long* gl =
            (const unsigned long long*)(slots + (size_t)(u >= 2 ? u - 2 : 0) * NBLK);
        unsigned long long gv = 0xB0000000B0ull;       // sentinel-passing dummy
        if (u >= 2)
            gv = __hip_atomic_load(&gl[lane], __ATOMIC_RELAXED,
                                   __HIP_MEMORY_SCOPE_AGENT);

        // ---- decode x bits for step u ----
        uint32_t cwd[4] = {cw.x, cw.y, cw.z, cw.w};
        float xf[CPL];
        #pragma unroll
        for (int j = 0; j < CPL; ++j)
            xf[j] = (float)((cwd[j >> 2] >> ((j & 3) * 8)) & 1u);

        // ---- A-dots (4 rows), exact per-lane order as r1-r9 ----
        float dA0 = 0, dA1 = 0, dA2 = 0, dA3 = 0;
        #pragma unroll
        for (int j = 0; j < CPL; ++j) {
            dA0 += xf[j] * wA0[j];         // exact: x in {0,1}
            dA1 += xf[j] * wA1[j];
            dA2 += xf[j] * wA2[j];
            dA3 += xf[j] * wA3[j];
        }
        // ---- B-dots only for diverged rows (wave-uniform branch) ----
        float dB0 = dA0, dB1 = dA1, dB2 = dA2, dB3 = dA3;
        if (!rfl(eq0)) { dB0 = 0;
            #pragma unroll
            for (int j = 0; j < CPL; ++j) dB0 += xf[j] * wB0[j]; }
        if (!rfl(eq1)) { dB1 = 0;
            #pragma unroll
            for (int j = 0; j < CPL; ++j) dB1 += xf[j] * wB1[j]; }
        if (!rfl(eq2)) { dB2 = 0;
            #pragma unroll
            for (int j = 0; j < CPL; ++j) dB2 += xf[j] * wB2[j]; }
        if (!rfl(eq3)) { dB3 = 0;
            #pragma unroll
            for (int j = 0; j < CPL; ++j) dB3 += xf[j] * wB3[j]; }

        float dotA0, dotA1, dotA2, dotA3, dotB0, dotB1, dotB2, dotB3;
        fold4(dA0, dA1, dA2, dA3, dotA0, dotA1, dotA2, dotA3);
        bool alleq = eq0 && eq1 && eq2 && eq3;
        if (rfl(alleq)) {
            dotB0 = dotA0; dotB1 = dotA1; dotB2 = dotA2; dotB3 = dotA3;
        } else {
            fold4(dB0, dB1, dB2, dB3, dotB0, dotB1, dotB2, dotB3);
        }

        // ---- 4 hypotheses per row (d = P[u-1] branch, c = P[u] branch) ----
#define HYP(R)                                                                \
        float sa##R = memA##R + dotA##R;                                      \
        float sb##R = memB##R + dotB##R;                                      \
        float m00_##R = fmaxf(sa##R, 0.0f);                                   \
        float m01_##R = fmaxf(sa##R - PROHIB_F, 0.0f);                        \
        float m10_##R = fmaxf(sb##R, 0.0f);                                   \
        float m11_##R = fmaxf(sb##R - PROHIB_F, 0.0f);                        \
        bool s00_##R = m00_##R >= VTHR_F;                                     \
        bool s01_##R = m01_##R >= VTHR_F;                                     \
        bool s10_##R = m10_##R >= VTHR_F;                                     \
        bool s11_##R = m11_##R >= VTHR_F;
        HYP(0) HYP(1) HYP(2) HYP(3)
#undef HYP
        int hb = ((s00_0 || s00_1 || s00_2 || s00_3) ? 1 : 0) |
                 ((s01_0 || s01_1 || s01_2 || s01_3) ? 2 : 0) |
                 ((s10_0 || s10_1 || s10_2 || s10_3) ? 4 : 0) |
                 ((s11_0 || s11_1 || s11_2 || s11_3) ? 8 : 0);

        // ---- publish hb(u) IMMEDIATELY (before resolving P[u-1]) ----
        if (lane == 0)
            __hip_atomic_store(&slots[(size_t)u * NBLK + blk],
                               0xB0u | (uint32_t)hb,
                               __ATOMIC_RELAXED, __HIP_MEMORY_SCOPE_AGENT);

        // ---- resolve P[u-1] from line(u-2): whole-wave spin + recurrence ----
        int bst = 0;
        if (u >= 2) {
            bool ok = ((gv & 0xF0000000F0ull) == 0xB0000000B0ull);
            while (!__all(ok)) {
                gv = __hip_atomic_load(&gl[lane], __ATOMIC_RELAXED,
                                       __HIP_MEMORY_SCOPE_AGENT);
                ok = ((gv & 0xF0000000F0ull) == 0xB0000000B0ull);
            }
            uint32_t comb = (uint32_t)gv | (uint32_t)(gv >> 32);
            int kk = (p3 << 1) | p2;                   // (P[u-3]<<1)|P[u-2]
            bst = __any((int)((comb >> kk) & 1u));     // = P[u-1]
        }
        p3 = p2; p2 = bst;

        // ---- per-row: collapse d=bst, new membranes, eqNext ----
#define TAIL(R)                                                               \
        bool sprv##R = bst ? psB##R : psA##R;                                 \
        bool sc0_##R = bst ? s10_##R : s00_##R;                               \
        bool sc1_##R = bst ? s11_##R : s01_##R;                               \
        float mc0_##R = bst ? m10_##R : m00_##R;                              \
        float mc1_##R = bst ? m11_##R : m01_##R;                              \
        memA##R = sc0_##R ? 0.0f : mc0_##R;                                   \
        memB##R = sc1_##R ? 0.0f : mc1_##R;                                   \
        bool eqN##R = (sc0_##R == sc1_##R) && (memA##R == memB##R);
        TAIL(0) TAIL(1) TAIL(2) TAIL(3)
#undef TAIL

        if (u >= 1 && lane == 0)
            *(float4*)(out + (size_t)(u - 1) * COUT + row0) =
                make_float4(sprv0 ? 1.0f : 0.0f, sprv1 ? 1.0f : 0.0f,
                            sprv2 ? 1.0f : 0.0f, sprv3 ? 1.0f : 0.0f);

        // ---- lazy pf decode (only if some row potentiates) ----
        float pf[CPL];
        bool needPf = sc0_0 | sc1_0 | sc0_1 | sc1_1 |
                      sc0_2 | sc1_2 | sc0_3 | sc1_3;
        if (rfl(needPf)) {
            #pragma unroll
            for (int j = 0; j < CPL; ++j)
                pf[j] = (float)((cwd[j >> 2] >> ((j & 3) * 8 + 1)) & 3u);
        }

        // ---- weight updates: wave-uniform branches, only taken path issues
        auto upd = [&](float (&wAr)[CPL], float (&wBr)[CPL], bool& eqR,
                       bool sc0, bool sc1, bool sprv, bool eqN) {
            if (rfl((bst != 0) && !eqR)) {             // collapse to d-branch
                #pragma unroll
                for (int j = 0; j < CPL; ++j) wAr[j] = wBr[j];
            }
            if (rfl(eqN)) {
                if (rfl(sc0)) {                        // potentiate (common)
                    #pragma unroll
                    for (int j = 0; j < CPL; ++j)
                        wAr[j] = fminf(wAr[j] + pf[j], 127.0f);
                } else if (rfl(sprv)) {                // depress
                    #pragma unroll
                    for (int j = 0; j < CPL; ++j)
                        wAr[j] = fmaxf(wAr[j] - xf[j], 0.0f);
                }
                // wB stale; eq flag covers it
            } else {
                if (rfl(sc1)) {                        // c=1 into wB (from base)
                    #pragma unroll
                    for (int j = 0; j < CPL; ++j)
                        wBr[j] = fminf(wAr[j] + pf[j], 127.0f);
                } else if (rfl(sprv)) {
                    #pragma unroll
                    for (int j = 0; j < CPL; ++j)
                        wBr[j] = fmaxf(wAr[j] - xf[j], 0.0f);
                } else {
                    #pragma unroll
                    for (int j = 0; j < CPL; ++j) wBr[j] = wAr[j];
                }
                if (rfl(sc0)) {                        // c=0 in place
                    #pragma unroll
                    for (int j = 0; j < CPL; ++j)
                        wAr[j] = fminf(wAr[j] + pf[j], 127.0f);
                } else if (rfl(sprv)) {
                    #pragma unroll
                    for (int j = 0; j < CPL; ++j)
                        wAr[j] = fmaxf(wAr[j] - xf[j], 0.0f);
                }
            }
            eqR = eqN;
        };
        upd(wA0, wB0, eq0, sc0_0, sc1_0, sprv0, eqN0);
        upd(wA1, wB1, eq1, sc0_1, sc1_1, sprv1, eqN1);
        upd(wA2, wB2, eq2, sc0_2, sc1_2, sprv2, eqN2);
        upd(wA3, wB3, eq3, sc0_3, sc1_3, sprv3, eqN3);
        psA0 = sc0_0; psA1 = sc0_1; psA2 = sc0_2; psA3 = sc0_3;
        psB0 = sc1_0; psB1 = sc1_1; psB2 = sc1_2; psB3 = sc1_3;

        uint4 cw2 = (u + 2 < T_STEPS) ? code4[(size_t)(u + 2) * 64 + lane]
                                      : make_uint4(0u, 0u, 0u, 0u);
        cw = cwn; cwn = cw2;
    }

    // ---- epilogue: resolve P[T-1] from line(T-2) and write out(T-1) ----
    {
        const unsigned long long* gl2 =
            (const unsigned long long*)(slots + (size_t)(T_STEPS - 2) * NBLK);
        unsigned long long gv2;
        bool ok;
        do {
            gv2 = __hip_atomic_load(&gl2[lane], __ATOMIC_RELAXED,
                                    __HIP_MEMORY_SCOPE_AGENT);
            ok = ((gv2 & 0xF0000000F0ull) == 0xB0000000B0ull);
        } while (!__all(ok));
        uint32_t comb = (uint32_t)gv2 | (uint32_t)(gv2 >> 32);
        int kk = (p3 << 1) | p2;
        int cst = __any((int)((comb >> kk) & 1u));
        if (lane == 0) {
            bool r0 = cst ? psB0 : psA0;
            bool r1 = cst ? psB1 : psA1;
            bool r2 = cst ? psB2 : psA2;
            bool r3 = cst ? psB3 : psA3;
            *(float4*)(out + (size_t)(T_STEPS - 1) * COUT + row0) =
                make_float4(r0 ? 1.0f : 0.0f, r1 ? 1.0f : 0.0f,
                            r2 ? 1.0f : 0.0f, r3 ? 1.0f : 0.0f);
        }
    }
}

extern "C" void kernel_launch(void* const* d_in, const int* in_sizes, int n_in,
                              void* d_out, int out_size, void* d_ws, size_t ws_size,
                              hipStream_t stream) {
    const int*   x      = (const int*)d_in[0];     // (T,1,CIN) int32
    const float* weight = (const float*)d_in[1];   // (COUT,CIN) f32
    float* out = (float*)d_out;                    // (T,1,COUT) f32

    uint32_t* slots = (uint32_t*)d_ws;
    uint8_t*  code  = (uint8_t*)d_ws + CODE_OFFSET;

    int prep_threads = T_STEPS * 64;
    prep_kernel<<<(prep_threads + 255) / 256, 256, 0, stream>>>(x, code,
                                                                (uint2*)slots);
    snn_kernel<<<NBLK, 64, 0, stream>>>(weight, code, slots, out);
}

// Round 11
// 1652.283 us; speedup vs baseline: 1.5808x; 1.5808x over previous
//
#include <hip/hip_runtime.h>
#include <stdint.h>

// Net_11587821765063: sequential SNN scan, T=1000 steps.
// Output = spike_out (T,1,COUT) float32 only; w / traces are not returned.
//
// Math reductions (absmax 0 in rounds 1-10):
//  - potentiation p[t][i] = 2 if x[t][i] else (1 if (t==0 or x[t-1][i]) else 0)
//  - depression for row o at t = -x[t][i] iff (!spike[t][o] && spike[t-1][o]),
//    spike[-1] := true (cout init quirk).
//  - prohibit P[t] = 1 iff any spike at t-1 (grid-wide 1-bit OR); P[0]=0.
//
// Round 11 = r7 (best: 128 blocks x 4 waves x 1 row/wave, branchy-lean
// updates, 2-step speculation) + PUBLISH-EARLY via split barrier.
// r7's serial chain was resolve(P[u-1]) -> publish(u) (spin precedes the
// publish store in wave0's program order), giving period = Δ/2, Δ≈3500 cyc.
// New order: sh_h -> barrier A -> publish hb(u) (independent of resolve) ->
// spin/resolve P[u-1] -> sh_b -> barrier B -> finalize. The recurrence chain
// now spans 3 steps: 3p >= C1 + Δ + C2 -> p ≈ (900+3500)/3 ≈ 1500 cyc.
// Published values, recurrence, and every FP sequence are bit-identical to
// r7; only the timing changes. s_sleep(1) backoff retained (outlier killer).

#define T_STEPS 1000
#define CIN     784
#define COUT    512
#define CPL     13            // columns per lane (64*13 = 832 >= 784)
#define NBLK    128
#define WPB     4             // waves per block, 1 row per wave
#define VTHR_F   12500.0f
#define PROHIB_F 11250.0f

#define SLOTS_WORDS (T_STEPS * NBLK)          // uint32 per (u, blk) = 128000
#define CODE_OFFSET 524288                    // 512 KiB >= 512000 B of slots

// ---- prep: zero slot words and pack per-(t,lane) 16-byte code slot:
// byte j (j<13) encodes col = lane*13+j: bit0 = x[t][col], bits[2:1] = p.
__global__ __launch_bounds__(256) void prep_kernel(const int* __restrict__ x,
                                                   uint8_t* __restrict__ code,
                                                   uint2* __restrict__ slots2) {
    int gid = blockIdx.x * blockDim.x + threadIdx.x;   // one per (t, lane)
    if (gid >= T_STEPS * 64) return;
    slots2[gid] = make_uint2(0u, 0u);                  // 64000 x 8B = 512000 B
    int t = gid >> 6;
    int lane = gid & 63;
    uint32_t wds[4] = {0u, 0u, 0u, 0u};
    #pragma unroll
    for (int j = 0; j < CPL; ++j) {
        int col = lane * CPL + j;
        uint32_t b = 0u;
        if (col < CIN) {
            int xc = x[t * CIN + col];
            int xp = (t > 0) ? x[(t - 1) * CIN + col] : 0;
            int p = xc ? 2 : ((t == 0) ? 1 : (xp ? 1 : 0));
            b = (uint32_t)((xc & 1) | (p << 1));
        }
        wds[j >> 2] |= b << ((j & 3) * 8);
    }
    ((uint4*)code)[gid] = make_uint4(wds[0], wds[1], wds[2], wds[3]);
}

__device__ __forceinline__ int rfl(bool b) {      // force SGPR / s_cbranch
    return __builtin_amdgcn_readfirstlane(b ? 1 : 0);
}

__global__ __launch_bounds__(256, 1) void snn_kernel(const float* __restrict__ weight,
                                                     const uint8_t* __restrict__ code,
                                                     uint32_t* __restrict__ slots,
                                                     float* __restrict__ out) {
    __shared__ int sh_h[2][WPB];    // double-buffered per-wave hypothesis bits
    __shared__ int sh_b[2];         // double-buffered resolved branch bit

    const int tid  = threadIdx.x;
    const int wave = tid >> 6;
    const int lane = tid & 63;
    const int blk  = blockIdx.x;
    const int row  = blk * WPB + wave;

    float wA[CPL], wB[CPL];
    #pragma unroll
    for (int j = 0; j < CPL; ++j) {
        int col = lane * CPL + j;
        float v = (col < CIN) ? weight[row * CIN + col] : 0.0f;
        wA[j] = v; wB[j] = v;
    }

    const uint4* code4 = (const uint4*)code;
    uint4 cw  = code4[lane];               // codes for u=0
    uint4 cwn = code4[64 + lane];          // codes for u=1 (prefetch)

    float memA = 0.0f, memB = 0.0f;
    bool  psA = true, psB = true;          // spike(-1)=true quirk
    bool  eq  = true;                      // wB == wA (and memB==memA, psB==psA)
    int p2 = 0, p3 = 0;                    // wave0: actual P[u-2], P[u-3]

    for (int u = 0; u < T_STEPS; ++u) {
        // ---- wave0: early prefetch of line(u-2): 64 lanes x 8B = 128 dwords
        const unsigned long long* gl =
            (const unsigned long long*)(slots + (size_t)(u >= 2 ? u - 2 : 0) * NBLK);
        unsigned long long gv = 0xB0000000B0ull;       // sentinel-passing dummy
        if (wave == 0 && u >= 2)
            gv = __hip_atomic_load(&gl[lane], __ATOMIC_RELAXED,
                                   __HIP_MEMORY_SCOPE_AGENT);

        // ---- decode x bits for step u; dot(s) ----
        uint32_t cwd[4] = {cw.x, cw.y, cw.z, cw.w};
        float xf[CPL];
        #pragma unroll
        for (int j = 0; j < CPL; ++j)
            xf[j] = (float)((cwd[j >> 2] >> ((j & 3) * 8)) & 1u);
        float dA = 0.0f;
        #pragma unroll
        for (int j = 0; j < CPL; ++j) dA += xf[j] * wA[j];   // exact: x in {0,1}
        float dB;
        if (rfl(eq)) {
            dB = dA;                       // wB == wA -> bit-identical
        } else {
            dB = 0.0f;
            #pragma unroll
            for (int j = 0; j < CPL; ++j) dB += xf[j] * wB[j];
        }

        // ---- folded 2-value reduction (same xor tree shape as r1-r10) ----
        bool hi = (lane & 32) != 0;
        float k0 = hi ? dB : dA;
        float s0 = hi ? dA : dB;
        k0 += __shfl_xor(s0, 32, 64);
        k0 += __shfl_xor(k0, 16, 64);
        k0 += __shfl_xor(k0, 8, 64);
        k0 += __shfl_xor(k0, 4, 64);
        k0 += __shfl_xor(k0, 2, 64);
        k0 += __shfl_xor(k0, 1, 64);
        float ot = __shfl_xor(k0, 32, 64);
        float dotA = hi ? ot : k0;
        float dotB = hi ? k0 : ot;

        // ---- 4 hypotheses (d = P[u-1] branch, c = P[u] branch) ----
        float sa = memA + dotA;            // reference op order
        float sb = memB + dotB;
        float m00 = fmaxf(sa, 0.0f),            m01 = fmaxf(sa - PROHIB_F, 0.0f);
        float m10 = fmaxf(sb, 0.0f),            m11 = fmaxf(sb - PROHIB_F, 0.0f);
        bool s00 = m00 >= VTHR_F, s01 = m01 >= VTHR_F;
        bool s10 = m10 >= VTHR_F, s11 = m11 >= VTHR_F;
        int hb = (s00 ? 1 : 0) | (s01 ? 2 : 0) | (s10 ? 4 : 0) | (s11 ? 8 : 0);
        if (lane == 0) sh_h[u & 1][wave] = hb;

        __syncthreads();                               // barrier A: sh_h ready

        // ---- wave0: publish FIRST (independent of resolve), then resolve ----
        if (wave == 0) {
            if (lane == 0) {
                int hh = sh_h[u & 1][0] | sh_h[u & 1][1] |
                         sh_h[u & 1][2] | sh_h[u & 1][3];
                __hip_atomic_store(&slots[(size_t)u * NBLK + blk],
                                   0xB0u | (uint32_t)hh,
                                   __ATOMIC_RELAXED, __HIP_MEMORY_SCOPE_AGENT);
            }
            int bstar = 0;
            if (u >= 2) {
                bool ok = ((gv & 0xF0000000F0ull) == 0xB0000000B0ull);
                while (!__all(ok)) {
                    __builtin_amdgcn_s_sleep(1);       // backoff
                    gv = __hip_atomic_load(&gl[lane], __ATOMIC_RELAXED,
                                           __HIP_MEMORY_SCOPE_AGENT);
                    ok = ((gv & 0xF0000000F0ull) == 0xB0000000B0ull);
                }
                uint32_t comb = (uint32_t)gv | (uint32_t)(gv >> 32);
                int kk = (p3 << 1) | p2;               // (P[u-3]<<1)|P[u-2]
                bstar = __any((int)((comb >> kk) & 1u));
            }
            p3 = p2; p2 = bstar;
            if (lane == 0) sh_b[u & 1] = bstar;
        }
        __syncthreads();                               // barrier B: sh_b ready
        const int bst = sh_b[u & 1];                   // resolved P[u-1]

        // ---- collapse branch d=bst; emit out(u-1); rebranch over c=P[u] ----
        bool sprv = bst ? psB : psA;                   // actual spike(u-1)
        bool sc0  = bst ? s10 : s00;                   // spike under c=0
        bool sc1  = bst ? s11 : s01;                   // spike under c=1
        float mc0 = bst ? m10 : m00;
        float mc1 = bst ? m11 : m01;

        if (u >= 1 && lane == 0)
            out[(size_t)(u - 1) * COUT + row] = sprv ? 1.0f : 0.0f;

        memA = sc0 ? 0.0f : mc0;
        memB = sc1 ? 0.0f : mc1;
        bool eqNext = (sc0 == sc1) && (memA == memB);

        // collapse weights to the resolved d-branch (only if they differ)
        if (rfl(bst && !eq)) {
            #pragma unroll
            for (int j = 0; j < CPL; ++j) wA[j] = wB[j];
        }
        // wave-uniform branchy updates: only the taken path issues
        if (rfl(eqNext)) {
            if (rfl(sc0)) {                // potentiate (common path)
                #pragma unroll
                for (int j = 0; j < CPL; ++j) {
                    float pfj = (float)((cwd[j >> 2] >> ((j & 3) * 8 + 1)) & 3u);
                    wA[j] = fminf(wA[j] + pfj, 127.0f);
                }
            } else if (rfl(sprv)) {        // depress
                #pragma unroll
                for (int j = 0; j < CPL; ++j)
                    wA[j] = fmaxf(wA[j] - xf[j], 0.0f);
            }
            // wB stale; eq flag covers it
        } else {
            // divergent: build wB from pre-update wA base (c=1 path)
            if (rfl(sc1)) {
                #pragma unroll
                for (int j = 0; j < CPL; ++j) {
                    float pfj = (float)((cwd[j >> 2] >> ((j & 3) * 8 + 1)) & 3u);
                    wB[j] = fminf(wA[j] + pfj, 127.0f);
                }
            } else if (rfl(sprv)) {
                #pragma unroll
                for (int j = 0; j < CPL; ++j)
                    wB[j] = fmaxf(wA[j] - xf[j], 0.0f);
            } else {
                #pragma unroll
                for (int j = 0; j < CPL; ++j) wB[j] = wA[j];
            }
            if (rfl(sc0)) {                // c=0 path in place
                #pragma unroll
                for (int j = 0; j < CPL; ++j) {
                    float pfj = (float)((cwd[j >> 2] >> ((j & 3) * 8 + 1)) & 3u);
                    wA[j] = fminf(wA[j] + pfj, 127.0f);
                }
            } else if (rfl(sprv)) {
                #pragma unroll
                for (int j = 0; j < CPL; ++j)
                    wA[j] = fmaxf(wA[j] - xf[j], 0.0f);
            }
        }
        psA = sc0; psB = sc1; eq = eqNext;

        uint4 cw2 = (u + 2 < T_STEPS) ? code4[(size_t)(u + 2) * 64 + lane]
                                      : make_uint4(0u, 0u, 0u, 0u);
        cw = cwn; cwn = cw2;
    }

    // ---- epilogue: resolve P[T-1] and write out(T-1) ----
    {
        if (wave == 0) {
            const unsigned long long* gl2 =
                (const unsigned long long*)(slots + (size_t)(T_STEPS - 2) * NBLK);
            unsigned long long gv2;
            bool ok;
            do {
                gv2 = __hip_atomic_load(&gl2[lane], __ATOMIC_RELAXED,
                                        __HIP_MEMORY_SCOPE_AGENT);
                ok = ((gv2 & 0xF0000000F0ull) == 0xB0000000B0ull);
            } while (!__all(ok));
            uint32_t comb = (uint32_t)gv2 | (uint32_t)(gv2 >> 32);
            int kk = (p3 << 1) | p2;
            int cst = __any((int)((comb >> kk) & 1u));
            if (lane == 0) sh_b[T_STEPS & 1] = cst;
        }
        __syncthreads();
        int cst = sh_b[T_STEPS & 1];
        if (lane == 0) {
            bool sr = cst ? psB : psA;
            out[(size_t)(T_STEPS - 1) * COUT + row] = sr ? 1.0f : 0.0f;
        }
    }
}

extern "C" void kernel_launch(void* const* d_in, const int* in_sizes, int n_in,
                              void* d_out, int out_size, void* d_ws, size_t ws_size,
                              hipStream_t stream) {
    const int*   x      = (const int*)d_in[0];     // (T,1,CIN) int32
    const float* weight = (const float*)d_in[1];   // (COUT,CIN) f32
    float* out = (float*)d_out;                    // (T,1,COUT) f32

    uint32_t* slots = (uint32_t*)d_ws;
    uint8_t*  code  = (uint8_t*)d_ws + CODE_OFFSET;

    int prep_threads = T_STEPS * 64;
    prep_kernel<<<(prep_threads + 255) / 256, 256, 0, stream>>>(x, code,
                                                                (uint2*)slots);
    snn_kernel<<<NBLK, WPB * 64, 0, stream>>>(weight, code, slots, out);
}

// Round 12
// 1352.677 us; speedup vs baseline: 1.9309x; 1.2215x over previous
//
#include <hip/hip_runtime.h>
#include <stdint.h>

// Net_11587821765063: sequential SNN scan, T=1000 steps.
// Output = spike_out (T,1,COUT) float32 only; w / traces are not returned.
//
// Math reductions (absmax 0 in rounds 1-11):
//  - potentiation p[t][i] = 2 if x[t][i] else (1 if (t==0 or x[t-1][i]) else 0)
//  - depression for row o at t = -x[t][i] iff (!spike[t][o] && spike[t-1][o]),
//    spike[-1] := true (cout init quirk).
//  - prohibit P[t] = 1 iff any spike at t-1 (grid-wide 1-bit OR); P[0]=0.
//
// Round 12 = r7 (champion: 128 blocks x 4 waves x 1 row/wave, 2-step
// speculation, single barrier) + OR SHORT-CIRCUIT resolve:
//  P[u-1] = OR over all rows of spike(u-2). A block's own hb(u-2) bit
//  kk=(P[u-3]<<1)|P[u-2] is "my rows spiked at u-2 on the actual path".
//  If set -> P[u-1]=1 with NO gather/spin/MALL traffic (~99.98% of steps
//  given drive stats). Fallback: gather line(u-2) with early exit as soon
//  as ANY present dword has bit kk set (first-arrival, not last-arrival);
//  full sentinel wait only when the true answer is 0. Publishes remain
//  unconditional every step so the fallback is always serviceable.
//  Resolved P values are mathematically identical to r7 -> absmax 0.

#define T_STEPS 1000
#define CIN     784
#define COUT    512
#define CPL     13            // columns per lane (64*13 = 832 >= 784)
#define NBLK    128
#define WPB     4             // waves per block, 1 row per wave
#define VTHR_F   12500.0f
#define PROHIB_F 11250.0f

#define SLOTS_WORDS (T_STEPS * NBLK)          // uint32 per (u, blk) = 128000
#define CODE_OFFSET 524288                    // 512 KiB >= 512000 B of slots

// ---- prep: zero slot words and pack per-(t,lane) 16-byte code slot:
// byte j (j<13) encodes col = lane*13+j: bit0 = x[t][col], bits[2:1] = p.
__global__ __launch_bounds__(256) void prep_kernel(const int* __restrict__ x,
                                                   uint8_t* __restrict__ code,
                                                   uint2* __restrict__ slots2) {
    int gid = blockIdx.x * blockDim.x + threadIdx.x;   // one per (t, lane)
    if (gid >= T_STEPS * 64) return;
    slots2[gid] = make_uint2(0u, 0u);                  // 64000 x 8B = 512000 B
    int t = gid >> 6;
    int lane = gid & 63;
    uint32_t wds[4] = {0u, 0u, 0u, 0u};
    #pragma unroll
    for (int j = 0; j < CPL; ++j) {
        int col = lane * CPL + j;
        uint32_t b = 0u;
        if (col < CIN) {
            int xc = x[t * CIN + col];
            int xp = (t > 0) ? x[(t - 1) * CIN + col] : 0;
            int p = xc ? 2 : ((t == 0) ? 1 : (xp ? 1 : 0));
            b = (uint32_t)((xc & 1) | (p << 1));
        }
        wds[j >> 2] |= b << ((j & 3) * 8);
    }
    ((uint4*)code)[gid] = make_uint4(wds[0], wds[1], wds[2], wds[3]);
}

__device__ __forceinline__ int rfl(bool b) {      // force SGPR / s_cbranch
    return __builtin_amdgcn_readfirstlane(b ? 1 : 0);
}

__global__ __launch_bounds__(256, 1) void snn_kernel(const float* __restrict__ weight,
                                                     const uint8_t* __restrict__ code,
                                                     uint32_t* __restrict__ slots,
                                                     float* __restrict__ out) {
    __shared__ int sh_h[2][WPB];    // double-buffered per-wave hypothesis bits
    __shared__ int sh_b[2];         // double-buffered resolved branch bit

    const int tid  = threadIdx.x;
    const int wave = tid >> 6;
    const int lane = tid & 63;
    const int blk  = blockIdx.x;
    const int row  = blk * WPB + wave;

    float wA[CPL], wB[CPL];
    #pragma unroll
    for (int j = 0; j < CPL; ++j) {
        int col = lane * CPL + j;
        float v = (col < CIN) ? weight[row * CIN + col] : 0.0f;
        wA[j] = v; wB[j] = v;
    }

    const uint4* code4 = (const uint4*)code;
    uint4 cw  = code4[lane];               // codes for u=0
    uint4 cwn = code4[64 + lane];          // codes for u=1 (prefetch)

    float memA = 0.0f, memB = 0.0f;
    bool  psA = true, psB = true;          // spike(-1)=true quirk
    bool  eq  = true;                      // wB == wA (and memB==memA, psB==psA)
    int p2 = 0, p3 = 0;                    // wave0: actual P[u-2], P[u-3]
    int hh_m1 = 0, hh_m2 = 0;              // wave0: own hb(u-1), hb(u-2)

    for (int u = 0; u < T_STEPS; ++u) {
        // ---- wave0: self-decide check + gated prefetch of line(u-2) ----
        const int kk = (p3 << 1) | p2;                 // (P[u-3]<<1)|P[u-2]
        const bool selfdec = (u >= 2) && (((hh_m2 >> kk) & 1) != 0);
        const unsigned long long* gl =
            (const unsigned long long*)(slots + (size_t)(u >= 2 ? u - 2 : 0) * NBLK);
        unsigned long long gv = 0xB0000000B0ull;       // sentinel-passing dummy
        if (wave == 0 && u >= 2 && !selfdec)
            gv = __hip_atomic_load(&gl[lane], __ATOMIC_RELAXED,
                                   __HIP_MEMORY_SCOPE_AGENT);

        // ---- decode x bits for step u; dot(s) ----
        uint32_t cwd[4] = {cw.x, cw.y, cw.z, cw.w};
        float xf[CPL];
        #pragma unroll
        for (int j = 0; j < CPL; ++j)
            xf[j] = (float)((cwd[j >> 2] >> ((j & 3) * 8)) & 1u);
        float dA = 0.0f;
        #pragma unroll
        for (int j = 0; j < CPL; ++j) dA += xf[j] * wA[j];   // exact: x in {0,1}
        float dB;
        if (rfl(eq)) {
            dB = dA;                       // wB == wA -> bit-identical
        } else {
            dB = 0.0f;
            #pragma unroll
            for (int j = 0; j < CPL; ++j) dB += xf[j] * wB[j];
        }

        // ---- folded 2-value reduction (same xor tree shape as r1-r11) ----
        bool hi = (lane & 32) != 0;
        float k0 = hi ? dB : dA;
        float s0 = hi ? dA : dB;
        k0 += __shfl_xor(s0, 32, 64);
        k0 += __shfl_xor(k0, 16, 64);
        k0 += __shfl_xor(k0, 8, 64);
        k0 += __shfl_xor(k0, 4, 64);
        k0 += __shfl_xor(k0, 2, 64);
        k0 += __shfl_xor(k0, 1, 64);
        float ot = __shfl_xor(k0, 32, 64);
        float dotA = hi ? ot : k0;
        float dotB = hi ? k0 : ot;

        // ---- 4 hypotheses (d = P[u-1] branch, c = P[u] branch) ----
        float sa = memA + dotA;            // reference op order
        float sb = memB + dotB;
        float m00 = fmaxf(sa, 0.0f),            m01 = fmaxf(sa - PROHIB_F, 0.0f);
        float m10 = fmaxf(sb, 0.0f),            m11 = fmaxf(sb - PROHIB_F, 0.0f);
        bool s00 = m00 >= VTHR_F, s01 = m01 >= VTHR_F;
        bool s10 = m10 >= VTHR_F, s11 = m11 >= VTHR_F;
        int hb = (s00 ? 1 : 0) | (s01 ? 2 : 0) | (s10 ? 4 : 0) | (s11 ? 8 : 0);
        if (lane == 0) sh_h[u & 1][wave] = hb;

        // ---- wave0: resolve P[u-1] (self-decide / short-circuit gather) ----
        if (wave == 0) {
            int bstar = 0;
            if (u >= 2) {
                if (selfdec) {
                    bstar = 1;             // own rows spiked at u-2 -> OR is 1
                } else {
                    for (;;) {
                        bool pl = ((gv & 0xF0ull) == 0xB0ull);
                        bool ph = (((gv >> 32) & 0xF0ull) == 0xB0ull);
                        bool setl = pl && (((gv >> kk) & 1ull) != 0ull);
                        bool seth = ph && (((gv >> (32 + kk)) & 1ull) != 0ull);
                        if (__any((int)(setl || seth))) { bstar = 1; break; }
                        if (__all((int)(pl && ph))) {
                            uint32_t comb = (uint32_t)gv | (uint32_t)(gv >> 32);
                            bstar = __any((int)((comb >> kk) & 1u));
                            break;
                        }
                        __builtin_amdgcn_s_sleep(1);   // backoff
                        gv = __hip_atomic_load(&gl[lane], __ATOMIC_RELAXED,
                                               __HIP_MEMORY_SCOPE_AGENT);
                    }
                }
            }
            p3 = p2; p2 = bstar;
            if (lane == 0) sh_b[u & 1] = bstar;
        }
        __syncthreads();                               // single barrier per step

        // ---- wave0: publish + own-hb history shift (all wave0 lanes) ----
        if (wave == 0) {
            int hh = sh_h[u & 1][0] | sh_h[u & 1][1] |
                     sh_h[u & 1][2] | sh_h[u & 1][3];
            if (lane == 0)
                __hip_atomic_store(&slots[(size_t)u * NBLK + blk],
                                   0xB0u | (uint32_t)hh,
                                   __ATOMIC_RELAXED, __HIP_MEMORY_SCOPE_AGENT);
            hh_m2 = hh_m1; hh_m1 = hh;
        }
        const int bst = sh_b[u & 1];                   // resolved P[u-1]

        // ---- collapse branch d=bst; emit out(u-1); rebranch over c=P[u] ----
        bool sprv = bst ? psB : psA;                   // actual spike(u-1)
        bool sc0  = bst ? s10 : s00;                   // spike under c=0
        bool sc1  = bst ? s11 : s01;                   // spike under c=1
        float mc0 = bst ? m10 : m00;
        float mc1 = bst ? m11 : m01;

        if (u >= 1 && lane == 0)
            out[(size_t)(u - 1) * COUT + row] = sprv ? 1.0f : 0.0f;

        memA = sc0 ? 0.0f : mc0;
        memB = sc1 ? 0.0f : mc1;
        bool eqNext = (sc0 == sc1) && (memA == memB);

        // collapse weights to the resolved d-branch (only if they differ)
        if (rfl(bst && !eq)) {
            #pragma unroll
            for (int j = 0; j < CPL; ++j) wA[j] = wB[j];
        }
        // wave-uniform branchy updates: only the taken path issues
        if (rfl(eqNext)) {
            if (rfl(sc0)) {                // potentiate (common path)
                #pragma unroll
                for (int j = 0; j < CPL; ++j) {
                    float pfj = (float)((cwd[j >> 2] >> ((j & 3) * 8 + 1)) & 3u);
                    wA[j] = fminf(wA[j] + pfj, 127.0f);
                }
            } else if (rfl(sprv)) {        // depress
                #pragma unroll
                for (int j = 0; j < CPL; ++j)
                    wA[j] = fmaxf(wA[j] - xf[j], 0.0f);
            }
            // wB stale; eq flag covers it
        } else {
            // divergent: build wB from pre-update wA base (c=1 path)
            if (rfl(sc1)) {
                #pragma unroll
                for (int j = 0; j < CPL; ++j) {
                    float pfj = (float)((cwd[j >> 2] >> ((j & 3) * 8 + 1)) & 3u);
                    wB[j] = fminf(wA[j] + pfj, 127.0f);
                }
            } else if (rfl(sprv)) {
                #pragma unroll
                for (int j = 0; j < CPL; ++j)
                    wB[j] = fmaxf(wA[j] - xf[j], 0.0f);
            } else {
                #pragma unroll
                for (int j = 0; j < CPL; ++j) wB[j] = wA[j];
            }
            if (rfl(sc0)) {                // c=0 path in place
                #pragma unroll
                for (int j = 0; j < CPL; ++j) {
                    float pfj = (float)((cwd[j >> 2] >> ((j & 3) * 8 + 1)) & 3u);
                    wA[j] = fminf(wA[j] + pfj, 127.0f);
                }
            } else if (rfl(sprv)) {
                #pragma unroll
                for (int j = 0; j < CPL; ++j)
                    wA[j] = fmaxf(wA[j] - xf[j], 0.0f);
            }
        }
        psA = sc0; psB = sc1; eq = eqNext;

        uint4 cw2 = (u + 2 < T_STEPS) ? code4[(size_t)(u + 2) * 64 + lane]
                                      : make_uint4(0u, 0u, 0u, 0u);
        cw = cwn; cwn = cw2;
    }

    // ---- epilogue: resolve P[T-1] (self-decide / gather) and write out(T-1)
    {
        if (wave == 0) {
            const int kk = (p3 << 1) | p2;
            int cst;
            if (((hh_m2 >> kk) & 1) != 0) {
                cst = 1;                               // own rows forced the OR
            } else {
                const unsigned long long* gl2 =
                    (const unsigned long long*)(slots + (size_t)(T_STEPS - 2) * NBLK);
                unsigned long long gv2;
                for (;;) {
                    gv2 = __hip_atomic_load(&gl2[lane], __ATOMIC_RELAXED,
                                            __HIP_MEMORY_SCOPE_AGENT);
                    bool pl = ((gv2 & 0xF0ull) == 0xB0ull);
                    bool ph = (((gv2 >> 32) & 0xF0ull) == 0xB0ull);
                    bool setl = pl && (((gv2 >> kk) & 1ull) != 0ull);
                    bool seth = ph && (((gv2 >> (32 + kk)) & 1ull) != 0ull);
                    if (__any((int)(setl || seth))) { cst = 1; break; }
                    if (__all((int)(pl && ph))) {
                        uint32_t comb = (uint32_t)gv2 | (uint32_t)(gv2 >> 32);
                        cst = __any((int)((comb >> kk) & 1u));
                        break;
                    }
                    __builtin_amdgcn_s_sleep(1);
                }
            }
            if (lane == 0) sh_b[T_STEPS & 1] = cst;
        }
        __syncthreads();
        int cst = sh_b[T_STEPS & 1];
        if (lane == 0) {
            bool sr = cst ? psB : psA;
            out[(size_t)(T_STEPS - 1) * COUT + row] = sr ? 1.0f : 0.0f;
        }
    }
}

extern "C" void kernel_launch(void* const* d_in, const int* in_sizes, int n_in,
                              void* d_out, int out_size, void* d_ws, size_t ws_size,
                              hipStream_t stream) {
    const int*   x      = (const int*)d_in[0];     // (T,1,CIN) int32
    const float* weight = (const float*)d_in[1];   // (COUT,CIN) f32
    float* out = (float*)d_out;                    // (T,1,COUT) f32

    uint32_t* slots = (uint32_t*)d_ws;
    uint8_t*  code  = (uint8_t*)d_ws + CODE_OFFSET;

    int prep_threads = T_STEPS * 64;
    prep_kernel<<<(prep_threads + 255) / 256, 256, 0, stream>>>(x, code,
                                                                (uint2*)slots);
    snn_kernel<<<NBLK, WPB * 64, 0, stream>>>(weight, code, slots, out);
}

// Round 13
// 1211.240 us; speedup vs baseline: 2.1564x; 1.1168x over previous
//
#include <hip/hip_runtime.h>
#include <stdint.h>

// Net_11587821765063: sequential SNN scan, T=1000 steps.
// Output = spike_out (T,1,COUT) float32 only; w / traces are not returned.
//
// Math reductions (absmax 0 in rounds 1-12):
//  - potentiation p[t][i] = 2 if x[t][i] else (1 if (t==0 or x[t-1][i]) else 0)
//  - depression for row o at t = -x[t][i] iff (!spike[t][o] && spike[t-1][o]),
//    spike[-1] := true (cout init quirk).
//  - prohibit P[t] = 1 iff any spike at t-1 (grid-wide 1-bit OR); P[0]=0.
//
// Round 13 = r12 (champion: 128 blocks x 4 waves x 1 row/wave, 2-step
// speculation, OR short-circuit) with the exposed barrier-tail latencies
// removed:
//  1. out stores BATCHED to an epilogue (spike bits in registers: lane l
//     records step v when v%64==l) -> no stores in the loop body except
//     wave0's publish -> the barrier's vmcnt(0) drain is empty.
//  2. code prefetch issued at the TOP of iteration u (used at u+2).
//  3. symmetric resolve: every wave reads sh_h[u&1][0..3] (one 16B ds_read)
//     post-barrier, keeps its own hh/p2/p3 history and self-decides
//     P[u-1]=1 when the block's own hb(u-2) bit kk is set (~99.98% of
//     steps); rare fallback gathers globally per-wave. sh_b eliminated.
// All FP sequences identical to r12 (6-stage eq-case butterfly is value-
// identical to the 7-op fold with dB==dA) -> absmax 0.

#define T_STEPS 1000
#define CIN     784
#define COUT    512
#define CPL     13            // columns per lane (64*13 = 832 >= 784)
#define NBLK    128
#define WPB     4             // waves per block, 1 row per wave
#define VTHR_F   12500.0f
#define PROHIB_F 11250.0f

#define SLOTS_WORDS (T_STEPS * NBLK)          // uint32 per (u, blk) = 128000
#define CODE_OFFSET 524288                    // 512 KiB >= 512000 B of slots

// ---- prep: zero slot words and pack per-(t,lane) 16-byte code slot:
// byte j (j<13) encodes col = lane*13+j: bit0 = x[t][col], bits[2:1] = p.
__global__ __launch_bounds__(256) void prep_kernel(const int* __restrict__ x,
                                                   uint8_t* __restrict__ code,
                                                   uint2* __restrict__ slots2) {
    int gid = blockIdx.x * blockDim.x + threadIdx.x;   // one per (t, lane)
    if (gid >= T_STEPS * 64) return;
    slots2[gid] = make_uint2(0u, 0u);                  // 64000 x 8B = 512000 B
    int t = gid >> 6;
    int lane = gid & 63;
    uint32_t wds[4] = {0u, 0u, 0u, 0u};
    #pragma unroll
    for (int j = 0; j < CPL; ++j) {
        int col = lane * CPL + j;
        uint32_t b = 0u;
        if (col < CIN) {
            int xc = x[t * CIN + col];
            int xp = (t > 0) ? x[(t - 1) * CIN + col] : 0;
            int p = xc ? 2 : ((t == 0) ? 1 : (xp ? 1 : 0));
            b = (uint32_t)((xc & 1) | (p << 1));
        }
        wds[j >> 2] |= b << ((j & 3) * 8);
    }
    ((uint4*)code)[gid] = make_uint4(wds[0], wds[1], wds[2], wds[3]);
}

__device__ __forceinline__ int rfl(bool b) {      // force SGPR / s_cbranch
    return __builtin_amdgcn_readfirstlane(b ? 1 : 0);
}

__global__ __launch_bounds__(256, 1) void snn_kernel(const float* __restrict__ weight,
                                                     const uint8_t* __restrict__ code,
                                                     uint32_t* __restrict__ slots,
                                                     float* __restrict__ out) {
    __shared__ int sh_h[2][WPB];    // double-buffered per-wave hypothesis bits

    const int tid  = threadIdx.x;
    const int wave = tid >> 6;
    const int lane = tid & 63;
    const int blk  = blockIdx.x;
    const int row  = blk * WPB + wave;

    float wA[CPL], wB[CPL];
    #pragma unroll
    for (int j = 0; j < CPL; ++j) {
        int col = lane * CPL + j;
        float v = (col < CIN) ? weight[row * CIN + col] : 0.0f;
        wA[j] = v; wB[j] = v;
    }

    const uint4* code4 = (const uint4*)code;
    uint4 cw  = code4[lane];               // codes for u=0
    uint4 cwn = code4[64 + lane];          // codes for u=1 (prefetch)

    float memA = 0.0f, memB = 0.0f;
    bool  psA = true, psB = true;          // spike(-1)=true quirk
    bool  eq  = true;                      // wB == wA (and memB==memA, psB==psA)
    int p2 = 0, p3 = 0;                    // per-wave: actual P[u-2], P[u-3]
    int hh_m1 = 0, hh_m2 = 0;              // per-wave: block hh(u-1), hh(u-2)
    uint32_t myb = 0u;                     // spike bits for steps v: v%64==lane

    for (int u = 0; u < T_STEPS; ++u) {
        // ---- top-of-loop issues: code load for u+2, gated gather for u-2 ----
        uint4 cw2 = (u + 2 < T_STEPS) ? code4[(size_t)(u + 2) * 64 + lane]
                                      : make_uint4(0u, 0u, 0u, 0u);
        const int kk = (p3 << 1) | p2;                 // (P[u-3]<<1)|P[u-2]
        const bool selfdec = (u >= 2) && (((hh_m2 >> kk) & 1) != 0);
        const unsigned long long* gl =
            (const unsigned long long*)(slots + (size_t)(u >= 2 ? u - 2 : 0) * NBLK);
        unsigned long long gv = 0xB0000000B0ull;       // sentinel-passing dummy
        if (u >= 2 && !selfdec)
            gv = __hip_atomic_load(&gl[lane], __ATOMIC_RELAXED,
                                   __HIP_MEMORY_SCOPE_AGENT);

        // ---- decode x bits for step u; dot(s) ----
        uint32_t cwd[4] = {cw.x, cw.y, cw.z, cw.w};
        float xf[CPL];
        #pragma unroll
        for (int j = 0; j < CPL; ++j)
            xf[j] = (float)((cwd[j >> 2] >> ((j & 3) * 8)) & 1u);
        float dA = 0.0f;
        #pragma unroll
        for (int j = 0; j < CPL; ++j) dA += xf[j] * wA[j];   // exact: x in {0,1}

        float dotA, dotB;
        if (rfl(eq)) {
            // 6-stage butterfly on dA — value-identical to the 7-op fold
            // with dB==dA (validated r7/r12)
            float k0 = dA;
            k0 += __shfl_xor(k0, 32, 64);
            k0 += __shfl_xor(k0, 16, 64);
            k0 += __shfl_xor(k0, 8, 64);
            k0 += __shfl_xor(k0, 4, 64);
            k0 += __shfl_xor(k0, 2, 64);
            k0 += __shfl_xor(k0, 1, 64);
            dotA = k0; dotB = k0;
        } else {
            float dB = 0.0f;
            #pragma unroll
            for (int j = 0; j < CPL; ++j) dB += xf[j] * wB[j];
            bool hi = (lane & 32) != 0;
            float k0 = hi ? dB : dA;
            float s0 = hi ? dA : dB;
            k0 += __shfl_xor(s0, 32, 64);
            k0 += __shfl_xor(k0, 16, 64);
            k0 += __shfl_xor(k0, 8, 64);
            k0 += __shfl_xor(k0, 4, 64);
            k0 += __shfl_xor(k0, 2, 64);
            k0 += __shfl_xor(k0, 1, 64);
            float ot = __shfl_xor(k0, 32, 64);
            dotA = hi ? ot : k0;
            dotB = hi ? k0 : ot;
        }

        // ---- 4 hypotheses (d = P[u-1] branch, c = P[u] branch) ----
        float sa = memA + dotA;            // reference op order
        float sb = memB + dotB;
        float m00 = fmaxf(sa, 0.0f),            m01 = fmaxf(sa - PROHIB_F, 0.0f);
        float m10 = fmaxf(sb, 0.0f),            m11 = fmaxf(sb - PROHIB_F, 0.0f);
        bool s00 = m00 >= VTHR_F, s01 = m01 >= VTHR_F;
        bool s10 = m10 >= VTHR_F, s11 = m11 >= VTHR_F;
        int hb = (s00 ? 1 : 0) | (s01 ? 2 : 0) | (s10 ? 4 : 0) | (s11 ? 8 : 0);
        if (lane == 0) sh_h[u & 1][wave] = hb;

        __syncthreads();                   // single barrier; vmcnt drain empty

        // ---- all waves: read the 4 hypothesis words, OR, publish (wave0) ----
        int4 hv = *((const int4*)&sh_h[u & 1][0]);
        int hh = hv.x | hv.y | hv.z | hv.w;
        if (wave == 0 && lane == 0)
            __hip_atomic_store(&slots[(size_t)u * NBLK + blk],
                               0xB0u | (uint32_t)hh,
                               __ATOMIC_RELAXED, __HIP_MEMORY_SCOPE_AGENT);

        // ---- resolve P[u-1]: self-decide (common) or global fallback ----
        int bst = 0;
        if (u >= 2) {
            if (selfdec) {
                bst = 1;                   // block's rows spiked at u-2
            } else {
                for (;;) {
                    bool pl = ((gv & 0xF0ull) == 0xB0ull);
                    bool ph = (((gv >> 32) & 0xF0ull) == 0xB0ull);
                    bool setl = pl && (((gv >> kk) & 1ull) != 0ull);
                    bool seth = ph && (((gv >> (32 + kk)) & 1ull) != 0ull);
                    if (__any((int)(setl || seth))) { bst = 1; break; }
                    if (__all((int)(pl && ph))) {
                        uint32_t comb = (uint32_t)gv | (uint32_t)(gv >> 32);
                        bst = __any((int)((comb >> kk) & 1u));
                        break;
                    }
                    __builtin_amdgcn_s_sleep(1);       // backoff (rare path)
                    gv = __hip_atomic_load(&gl[lane], __ATOMIC_RELAXED,
                                           __HIP_MEMORY_SCOPE_AGENT);
                }
            }
        }
        p3 = p2; p2 = bst;
        hh_m2 = hh_m1; hh_m1 = hh;

        // ---- collapse branch d=bst; record out bit; rebranch over c=P[u] ----
        bool sprv = bst ? psB : psA;                   // actual spike(u-1)
        bool sc0  = bst ? s10 : s00;                   // spike under c=0
        bool sc1  = bst ? s11 : s01;                   // spike under c=1
        float mc0 = bst ? m10 : m00;
        float mc1 = bst ? m11 : m01;

        if (u >= 1) {
            int v = u - 1;
            if ((v & 63) == lane) myb |= (sprv ? 1u : 0u) << (v >> 6);
        }

        memA = sc0 ? 0.0f : mc0;
        memB = sc1 ? 0.0f : mc1;
        bool eqNext = (sc0 == sc1) && (memA == memB);

        // collapse weights to the resolved d-branch (only if they differ)
        if (rfl(bst && !eq)) {
            #pragma unroll
            for (int j = 0; j < CPL; ++j) wA[j] = wB[j];
        }
        // wave-uniform branchy updates: only the taken path issues
        if (rfl(eqNext)) {
            if (rfl(sc0)) {                // potentiate (common path)
                #pragma unroll
                for (int j = 0; j < CPL; ++j) {
                    float pfj = (float)((cwd[j >> 2] >> ((j & 3) * 8 + 1)) & 3u);
                    wA[j] = fminf(wA[j] + pfj, 127.0f);
                }
            } else if (rfl(sprv)) {        // depress
                #pragma unroll
                for (int j = 0; j < CPL; ++j)
                    wA[j] = fmaxf(wA[j] - xf[j], 0.0f);
            }
            // wB stale; eq flag covers it
        } else {
            // divergent: build wB from pre-update wA base (c=1 path)
            if (rfl(sc1)) {
                #pragma unroll
                for (int j = 0; j < CPL; ++j) {
                    float pfj = (float)((cwd[j >> 2] >> ((j & 3) * 8 + 1)) & 3u);
                    wB[j] = fminf(wA[j] + pfj, 127.0f);
                }
            } else if (rfl(sprv)) {
                #pragma unroll
                for (int j = 0; j < CPL; ++j)
                    wB[j] = fmaxf(wA[j] - xf[j], 0.0f);
            } else {
                #pragma unroll
                for (int j = 0; j < CPL; ++j) wB[j] = wA[j];
            }
            if (rfl(sc0)) {                // c=0 path in place
                #pragma unroll
                for (int j = 0; j < CPL; ++j) {
                    float pfj = (float)((cwd[j >> 2] >> ((j & 3) * 8 + 1)) & 3u);
                    wA[j] = fminf(wA[j] + pfj, 127.0f);
                }
            } else if (rfl(sprv)) {
                #pragma unroll
                for (int j = 0; j < CPL; ++j)
                    wA[j] = fmaxf(wA[j] - xf[j], 0.0f);
            }
        }
        psA = sc0; psB = sc1; eq = eqNext;

        cw = cwn; cwn = cw2;
    }

    // ---- epilogue: resolve P[T-1], record last bit, write all outputs ----
    {
        const int kk = (p3 << 1) | p2;
        int cst;
        if (((hh_m2 >> kk) & 1) != 0) {
            cst = 1;                       // block's rows forced the OR
        } else {
            const unsigned long long* gl2 =
                (const unsigned long long*)(slots + (size_t)(T_STEPS - 2) * NBLK);
            unsigned long long gv2;
            for (;;) {
                gv2 = __hip_atomic_load(&gl2[lane], __ATOMIC_RELAXED,
                                        __HIP_MEMORY_SCOPE_AGENT);
                bool pl = ((gv2 & 0xF0ull) == 0xB0ull);
                bool ph = (((gv2 >> 32) & 0xF0ull) == 0xB0ull);
                bool setl = pl && (((gv2 >> kk) & 1ull) != 0ull);
                bool seth = ph && (((gv2 >> (32 + kk)) & 1ull) != 0ull);
                if (__any((int)(setl || seth))) { cst = 1; break; }
                if (__all((int)(pl && ph))) {
                    uint32_t comb = (uint32_t)gv2 | (uint32_t)(gv2 >> 32);
                    cst = __any((int)((comb >> kk) & 1u));
                    break;
                }
                __builtin_amdgcn_s_sleep(1);
            }
        }
        bool sr = cst ? psB : psA;
        {
            int v = T_STEPS - 1;
            if ((v & 63) == lane) myb |= (sr ? 1u : 0u) << (v >> 6);
        }
        // write this row's 1000 spike floats from the bit register
        #pragma unroll
        for (int b = 0; b < 16; ++b) {
            int s = b * 64 + lane;
            if (s < T_STEPS)
                out[(size_t)s * COUT + row] = (float)((myb >> b) & 1u);
        }
    }
}

extern "C" void kernel_launch(void* const* d_in, const int* in_sizes, int n_in,
                              void* d_out, int out_size, void* d_ws, size_t ws_size,
                              hipStream_t stream) {
    const int*   x      = (const int*)d_in[0];     // (T,1,CIN) int32
    const float* weight = (const float*)d_in[1];   // (COUT,CIN) f32
    float* out = (float*)d_out;                    // (T,1,COUT) f32

    uint32_t* slots = (uint32_t*)d_ws;
    uint8_t*  code  = (uint8_t*)d_ws + CODE_OFFSET;

    int prep_threads = T_STEPS * 64;
    prep_kernel<<<(prep_threads + 255) / 256, 256, 0, stream>>>(x, code,
                                                                (uint2*)slots);
    snn_kernel<<<NBLK, WPB * 64, 0, stream>>>(weight, code, slots, out);
}